// Round 9
// baseline (256.481 us; speedup 1.0000x reference)
//
#include <hip/hip_runtime.h>
#include <hip/hip_bf16.h>

#define N_NODES 100000
#define N_EDGES 600000
#define FEAT 128
#define NUM_RELS 8
#define NUM_BASES 4
#define NBE 2344    // ceil(N_EDGES/256)

// grid partition for k_prep
#define PREP_CAST 6250                   // cast_h blocks (6250*256*8 = 12.8M bf16)
#define PREP_BLDB 320                    // build_b blocks (320*256 = 81920 = 5*128*128)
#define PREP_ZERO 392                    // cnt (100000) + scan status (128) zero blocks
#define PREP_GRID (PREP_CAST + PREP_BLDB + PREP_ZERO)

#define SCAN_TILES 98                    // ceil(25000 int4 / 256)

typedef short bf16x8 __attribute__((ext_vector_type(8)));
typedef float f32x4  __attribute__((ext_vector_type(4)));
typedef float f32x2  __attribute__((ext_vector_type(2)));

__device__ inline short f2bf(float x) {
    __hip_bfloat16 b = __float2bfloat16(x);
    return *reinterpret_cast<short*>(&b);
}

// ws layout (bytes):
//   hb     bf16[N*128]       @ 0            25,600,000
//   Btf    bf16[5*128*128]   @ 25,600,000   163,840   (FRAGMENT-MAJOR, see k_prep)
//   z      bf16[N*512]       @ 25,763,840   102,400,000  ([d][b*128+i])
//   packed int[E]            @ 128,163,840  2,400,000 (dst-sorted (src<<3)|rel)
//   cnt    int[N]            @ 130,563,840  400,000
//   offs   int[N+1 pad]      @ 130,963,840  400,128
//   cursor int[N]            @ 131,363,968  400,000
//   status int[128]          @ 131,763,968  512      (lookback-scan tile status)
// total ~131.8 MB

// ---------- k_prep: cast h->bf16 | build fragment-major B | zero cnt+status ----------
// Btf stored in EXACT per-lane MFMA fragment order (verified rounds 3-8):
//   lane l (quad=l>>4, n16=l&15) of frag (kc,ks,nt) holds
//   Bt[kc][o=n16*8+nt][ip=ks*32+quad*8 .. +8)   (Bt[o][i] = B[i][o])
// Position (in shorts): ((kc*4+ks)*8 + nt)*512 + lane*8 + j.
__global__ __launch_bounds__(256) void k_prep(const float* __restrict__ h,
                                              const float* __restrict__ weight,
                                              const float* __restrict__ rw,
                                              short* __restrict__ hb,
                                              short* __restrict__ Btf,
                                              int* __restrict__ cnt,
                                              int* __restrict__ status) {
    int b = blockIdx.x;
    if (b < PREP_CAST) {
        int i = b * 256 + threadIdx.x;                 // < 1.6M exactly
        const float4* h4 = (const float4*)h;
        float4 v0 = h4[2 * i], v1 = h4[2 * i + 1];
        union { short s[8]; bf16x8 v; } u;
        u.s[0] = f2bf(v0.x); u.s[1] = f2bf(v0.y); u.s[2] = f2bf(v0.z); u.s[3] = f2bf(v0.w);
        u.s[4] = f2bf(v1.x); u.s[5] = f2bf(v1.y); u.s[6] = f2bf(v1.z); u.s[7] = f2bf(v1.w);
        ((bf16x8*)hb)[i] = u.v;
    } else if (b < PREP_CAST + PREP_BLDB) {
        int idx = (b - PREP_CAST) * 256 + threadIdx.x; // < 81920 exactly
        int kc = idx >> 14;
        int e  = idx & 16383;
        int o  = e >> 7, ip = e & 127;
        float v = (kc == 0) ? rw[ip * FEAT + o]
                            : weight[(kc - 1) * FEAT * FEAT + ip * FEAT + o];
        int nt = o & 7, n16 = o >> 3;
        int ks = ip >> 5, quad = (ip >> 3) & 3, j = ip & 7;
        int lane = quad * 16 + n16;
        Btf[((kc * 4 + ks) * 8 + nt) * 512 + lane * 8 + j] = f2bf(v);
    } else {
        int i = (b - PREP_CAST - PREP_BLDB) * 256 + threadIdx.x;
        if (i < N_NODES) cnt[i] = 0;
        else if (i - N_NODES < 128) status[i - N_NODES] = 0;
    }
}

// ---------- dst histogram ----------
__global__ __launch_bounds__(256) void k_hist_dst(const int* __restrict__ dst,
                                                  int* __restrict__ cnt) {
    int i = blockIdx.x * 256 + threadIdx.x;
    if (i < N_EDGES) atomicAdd(&cnt[dst[i]], 1);       // 100K bins, ~6/bin
}

// ---------- decoupled-lookback exclusive scan: WAVE-PARALLEL lookback ----------
__global__ __launch_bounds__(256) void k_scan_lb(const int* __restrict__ cnt,
                                                 int* __restrict__ offs,
                                                 int* __restrict__ cursor,
                                                 int* __restrict__ status) {
    __shared__ int wsum[4];
    __shared__ int bcast;
    int bid = blockIdx.x;
    int lane = threadIdx.x & 63, wid = threadIdx.x >> 6;
    const int N4 = N_NODES / 4;                        // 25000
    int i4 = bid * 256 + threadIdx.x;

    const int4* cnt4 = (const int4*)cnt;
    int4 v = (i4 < N4) ? cnt4[i4] : make_int4(0, 0, 0, 0);
    int s = v.x + v.y + v.z + v.w;
    int incl = s;
#pragma unroll
    for (int d = 1; d < 64; d <<= 1) {
        int t = __shfl_up(incl, d);
        if (lane >= d) incl += t;
    }
    if (lane == 63) wsum[wid] = incl;
    __syncthreads();
    int total = wsum[0] + wsum[1] + wsum[2] + wsum[3];

    if (threadIdx.x < 64) {                            // wave 0 does the lookback
        int excl = 0;
        if (bid > 0) {
            if (lane == 0)
                __hip_atomic_store(&status[bid], (total << 2) | 1,
                                   __ATOMIC_RELEASE, __HIP_MEMORY_SCOPE_AGENT);
            int winEnd = bid;                          // window covers [winEnd-64, winEnd)
            for (;;) {
                int idx = winEnd - 64 + lane;
                int st = 2;                            // idx<0: prefix 0, done
                if (idx >= 0) {
                    st = __hip_atomic_load(&status[idx],
                                           __ATOMIC_ACQUIRE, __HIP_MEMORY_SCOPE_AGENT);
                    while ((st & 3) == 0) {
                        __builtin_amdgcn_s_sleep(1);
                        st = __hip_atomic_load(&status[idx],
                                               __ATOMIC_ACQUIRE, __HIP_MEMORY_SCOPE_AGENT);
                    }
                }
                unsigned long long done = __ballot((st & 3) == 2);
                int contrib;
                if (done) {
                    int L = 63 - __builtin_clzll(done);    // nearest prefix-done
                    contrib = (lane >= L) ? (st >> 2) : 0; // lane L: prefix; above: aggregates
                } else {
                    contrib = st >> 2;                     // all aggregates, keep walking
                }
#pragma unroll
                for (int m = 1; m < 64; m <<= 1) contrib += __shfl_xor(contrib, m);
                excl += contrib;
                if (done) break;
                winEnd -= 64;
            }
        }
        if (lane == 0) {
            __hip_atomic_store(&status[bid], ((excl + total) << 2) | 2,
                               __ATOMIC_RELEASE, __HIP_MEMORY_SCOPE_AGENT);
            bcast = excl;
            if (bid == SCAN_TILES - 1) offs[N_NODES] = excl + total;   // == N_EDGES
        }
    }
    __syncthreads();
    int wexcl = 0;
#pragma unroll
    for (int w = 0; w < 4; ++w) if (w < wid) wexcl += wsum[w];
    int base = bcast + wexcl + incl - s;
    if (i4 < N4) {
        int4 ex;
        ex.x = base;
        ex.y = base + v.x;
        ex.z = base + v.x + v.y;
        ex.w = base + v.x + v.y + v.z;
        ((int4*)offs)[i4]   = ex;
        ((int4*)cursor)[i4] = ex;
    }
}

// ---------- scatter: dst-sorted packed (src<<3)|rel — one 4B word per edge ----------
__global__ __launch_bounds__(256) void k_scatter_sorted(const int* __restrict__ src,
                                                        const int* __restrict__ dst,
                                                        const int* __restrict__ rel,
                                                        int* __restrict__ cursor,
                                                        int* __restrict__ packed) {
    int e = blockIdx.x * 256 + threadIdx.x;
    if (e < N_EDGES) {
        int p = atomicAdd(&cursor[dst[e]], 1);         // ~6-way contention
        packed[p] = (src[e] << 3) | rel[e];
    }
}

// ---------- edge phase: z[d][b][:] = sum_{e->d} w_comp[rel,b] * h[src] ----------
// TWO dst streams per wave (verified round 6). Per-dst FP accumulation order is
// ascending edge index — bit-identical to the single-stream version.
#define RL(pk, j) __builtin_amdgcn_readlane(pk, j)
#define EDGE_ACC(zz, c, v)                                               \
    {   f32x2 hh; hh.x = __int_as_float((v) << 16);                      \
        hh.y = __int_as_float((v) & 0xffff0000u);                        \
        f32x2 cc;                                                        \
        cc = c.x; zz[0] += cc * hh;                                      \
        cc = c.y; zz[1] += cc * hh;                                      \
        cc = c.z; zz[2] += cc * hh;                                      \
        cc = c.w; zz[3] += cc * hh; }

__global__ __launch_bounds__(256) void k_edge_z(const int* __restrict__ offs,
                                                const int* __restrict__ packed,
                                                const float* __restrict__ wc,
                                                const short* __restrict__ hb,
                                                unsigned int* __restrict__ z_u32) {
    int wid = threadIdx.x >> 6, lane = threadIdx.x & 63;
    int d0 = blockIdx.x * 8 + wid * 2;                 // grid 12500 -> exact, no tail
    int s0 = offs[d0], sM = offs[d0 + 1], e1 = offs[d0 + 2];

    const float4* wc4 = (const float4*)wc;             // uniform idx -> s_load_dwordx4
    const unsigned int* hbu = (const unsigned int*)hb; // 64 u32 per node row

    f32x2 za[4] = {(f32x2)0.f, (f32x2)0.f, (f32x2)0.f, (f32x2)0.f};
    f32x2 zb[4] = {(f32x2)0.f, (f32x2)0.f, (f32x2)0.f, (f32x2)0.f};

    int baseA = s0, baseB = sM;
    while (baseA < sM || baseB < e1) {
        int mA = sM - baseA; mA = mA < 0 ? 0 : (mA > 64 ? 64 : mA);
        int mB = e1 - baseB; mB = mB < 0 ? 0 : (mB > 64 ? 64 : mB);
        int pkA = (lane < mA) ? packed[baseA + lane] : 0;
        int pkB = (lane < mB) ? packed[baseB + lane] : 0;
        int jA = 0, jB = 0;

        // joint 4+4: 8 independent gathers in flight
        while (jA + 3 < mA && jB + 3 < mB) {
            int a0 = RL(pkA, jA), a1 = RL(pkA, jA + 1), a2 = RL(pkA, jA + 2), a3 = RL(pkA, jA + 3);
            int b0 = RL(pkB, jB), b1 = RL(pkB, jB + 1), b2 = RL(pkB, jB + 2), b3 = RL(pkB, jB + 3);
            unsigned int va0 = hbu[(size_t)(a0 >> 3) * 64 + lane];
            unsigned int va1 = hbu[(size_t)(a1 >> 3) * 64 + lane];
            unsigned int va2 = hbu[(size_t)(a2 >> 3) * 64 + lane];
            unsigned int va3 = hbu[(size_t)(a3 >> 3) * 64 + lane];
            unsigned int vb0 = hbu[(size_t)(b0 >> 3) * 64 + lane];
            unsigned int vb1 = hbu[(size_t)(b1 >> 3) * 64 + lane];
            unsigned int vb2 = hbu[(size_t)(b2 >> 3) * 64 + lane];
            unsigned int vb3 = hbu[(size_t)(b3 >> 3) * 64 + lane];
            float4 ca0 = wc4[a0 & 7], ca1 = wc4[a1 & 7], ca2 = wc4[a2 & 7], ca3 = wc4[a3 & 7];
            float4 cb0 = wc4[b0 & 7], cb1 = wc4[b1 & 7], cb2 = wc4[b2 & 7], cb3 = wc4[b3 & 7];
            EDGE_ACC(za, ca0, va0); EDGE_ACC(za, ca1, va1);
            EDGE_ACC(za, ca2, va2); EDGE_ACC(za, ca3, va3);
            EDGE_ACC(zb, cb0, vb0); EDGE_ACC(zb, cb1, vb1);
            EDGE_ACC(zb, cb2, vb2); EDGE_ACC(zb, cb3, vb3);
            jA += 4; jB += 4;
        }
        // joint 1+1: overlap the two tails (2 in flight)
        while (jA < mA && jB < mB) {
            int a0 = RL(pkA, jA), b0 = RL(pkB, jB);
            unsigned int va0 = hbu[(size_t)(a0 >> 3) * 64 + lane];
            unsigned int vb0 = hbu[(size_t)(b0 >> 3) * 64 + lane];
            float4 ca0 = wc4[a0 & 7], cb0 = wc4[b0 & 7];
            EDGE_ACC(za, ca0, va0);
            EDGE_ACC(zb, cb0, vb0);
            ++jA; ++jB;
        }
        // drain A
        while (jA + 3 < mA) {
            int a0 = RL(pkA, jA), a1 = RL(pkA, jA + 1), a2 = RL(pkA, jA + 2), a3 = RL(pkA, jA + 3);
            unsigned int va0 = hbu[(size_t)(a0 >> 3) * 64 + lane];
            unsigned int va1 = hbu[(size_t)(a1 >> 3) * 64 + lane];
            unsigned int va2 = hbu[(size_t)(a2 >> 3) * 64 + lane];
            unsigned int va3 = hbu[(size_t)(a3 >> 3) * 64 + lane];
            float4 ca0 = wc4[a0 & 7], ca1 = wc4[a1 & 7], ca2 = wc4[a2 & 7], ca3 = wc4[a3 & 7];
            EDGE_ACC(za, ca0, va0); EDGE_ACC(za, ca1, va1);
            EDGE_ACC(za, ca2, va2); EDGE_ACC(za, ca3, va3);
            jA += 4;
        }
        while (jA < mA) {
            int a0 = RL(pkA, jA);
            unsigned int va0 = hbu[(size_t)(a0 >> 3) * 64 + lane];
            float4 ca0 = wc4[a0 & 7];
            EDGE_ACC(za, ca0, va0);
            ++jA;
        }
        // drain B
        while (jB + 3 < mB) {
            int b0 = RL(pkB, jB), b1 = RL(pkB, jB + 1), b2 = RL(pkB, jB + 2), b3 = RL(pkB, jB + 3);
            unsigned int vb0 = hbu[(size_t)(b0 >> 3) * 64 + lane];
            unsigned int vb1 = hbu[(size_t)(b1 >> 3) * 64 + lane];
            unsigned int vb2 = hbu[(size_t)(b2 >> 3) * 64 + lane];
            unsigned int vb3 = hbu[(size_t)(b3 >> 3) * 64 + lane];
            float4 cb0 = wc4[b0 & 7], cb1 = wc4[b1 & 7], cb2 = wc4[b2 & 7], cb3 = wc4[b3 & 7];
            EDGE_ACC(zb, cb0, vb0); EDGE_ACC(zb, cb1, vb1);
            EDGE_ACC(zb, cb2, vb2); EDGE_ACC(zb, cb3, vb3);
            jB += 4;
        }
        while (jB < mB) {
            int b0 = RL(pkB, jB);
            unsigned int vb0 = hbu[(size_t)(b0 >> 3) * 64 + lane];
            float4 cb0 = wc4[b0 & 7];
            EDGE_ACC(zb, cb0, vb0);
            ++jB;
        }
        baseA += 64; baseB += 64;
    }

    unsigned int* row0 = z_u32 + (size_t)d0 * 256;     // 512 bf16 = 256 u32
    unsigned int* row1 = row0 + 256;
#pragma unroll
    for (int b = 0; b < 4; ++b) {
        unsigned int lo0 = ((unsigned int)(unsigned short)f2bf(za[b].x));
        unsigned int hi0 = ((unsigned int)(unsigned short)f2bf(za[b].y)) << 16;
        row0[b * 64 + lane] = lo0 | hi0;
        unsigned int lo1 = ((unsigned int)(unsigned short)f2bf(zb[b].x));
        unsigned int hi1 = ((unsigned int)(unsigned short)f2bf(zb[b].y)) << 16;
        row1[b * 64 + lane] = lo1 | hi1;
    }
}

// ---------- fused GEMM: out = relu([hb | z] @ B + bias), K=640 ----------
// Round-8 structure + LIVENESS-PINNED upfront A prefetch. The 20 A loads
// (4 hb + 16 z fragments) are issued before the kc loop and PINNED with
// asm volatile("" : "+v") — the asm becomes the value's new definition, so the
// compiler can neither sink the loads into the loop nor rematerialize them
// (rounds 7/8 showed const-__restrict__ loads are otherwise freely sunk).
// One-time ~900cy HBM wait at the pin; kc loop then runs pure LDS+MFMA with
// only the L2-fast B-DMA drain per kc.
__global__ __launch_bounds__(256, 2) void k_gemm_fused(const short* __restrict__ hb,
                                                       const short* __restrict__ z,
                                                       const short* __restrict__ Btf,
                                                       const float* __restrict__ bias,
                                                       float* __restrict__ out) {
    __shared__ short lds[FEAT * FEAT];                  // 32 KB (one K-chunk, frag-major)
    int wave = threadIdx.x >> 6, lane = threadIdx.x & 63;
    int quad = lane >> 4, n16 = lane & 15;
    int base = blockIdx.x * 64 + wave * 16;

    int rowA = base + n16;
    if (rowA >= N_NODES) rowA = N_NODES - 1;

    // ---- issue ALL A loads upfront ----
    const bf16x8* hp = (const bf16x8*)(hb + (size_t)rowA * FEAT);
    const bf16x8* zp = (const bf16x8*)(z + (size_t)rowA * 512);
    bf16x8 ah[4];
#pragma unroll
    for (int ks = 0; ks < 4; ++ks) ah[ks] = hp[ks * 4 + quad];
    bf16x8 az[4][4];
#pragma unroll
    for (int kc = 0; kc < 4; ++kc)
#pragma unroll
        for (int ks = 0; ks < 4; ++ks) az[kc][ks] = zp[kc * 16 + ks * 4 + quad];

    // ---- PIN: forbid sinking/remat of the A values (rule #17 liveness pin) ----
#pragma unroll
    for (int ks = 0; ks < 4; ++ks)
        asm volatile("" : "+v"(ah[ks]));
#pragma unroll
    for (int kc = 0; kc < 4; ++kc)
#pragma unroll
        for (int ks = 0; ks < 4; ++ks)
            asm volatile("" : "+v"(az[kc][ks]));

    f32x4 acc[8];
#pragma unroll
    for (int nt = 0; nt < 8; ++nt) acc[nt] = (f32x4)0.f;

    const bf16x8* bp = (const bf16x8*)lds;
    char* lds_base = (char*)lds;

#pragma unroll
    for (int kc = 0; kc < 5; ++kc) {
        if (kc) __syncthreads();                        // drain reads before restage
        const char* gsrc = (const char*)Btf + kc * 32768;
#pragma unroll
        for (int t = 0; t < 8; ++t) {
            unsigned int off = wave * 8192 + t * 1024;
            __builtin_amdgcn_global_load_lds(
                (const __attribute__((address_space(1))) unsigned int*)(gsrc + off + lane * 16),
                (__attribute__((address_space(3))) unsigned int*)(lds_base + off),
                16, 0, 0);
        }
        __syncthreads();                                // DMA complete

#pragma unroll
        for (int ks = 0; ks < 4; ++ks) {
            bf16x8 a = (kc == 0) ? ah[ks] : az[kc - 1][ks];   // static after unroll
            const bf16x8* bks = bp + ks * 512 + lane;   // contiguous 1KB per frag
#pragma unroll
            for (int nt = 0; nt < 8; ++nt) {
                bf16x8 b = bks[nt * 64];
                acc[nt] = __builtin_amdgcn_mfma_f32_16x16x32_bf16(a, b, acc[nt], 0, 0, 0);
            }
        }
    }

    float bv[8];
#pragma unroll
    for (int nt = 0; nt < 8; ++nt) bv[nt] = bias[n16 * 8 + nt];

#pragma unroll
    for (int reg = 0; reg < 4; ++reg) {
        int node = base + quad * 4 + reg;
        if (node < N_NODES) {
            float4 fa, fb;
            fa.x = fmaxf(acc[0][reg] + bv[0], 0.f);
            fa.y = fmaxf(acc[1][reg] + bv[1], 0.f);
            fa.z = fmaxf(acc[2][reg] + bv[2], 0.f);
            fa.w = fmaxf(acc[3][reg] + bv[3], 0.f);
            fb.x = fmaxf(acc[4][reg] + bv[4], 0.f);
            fb.y = fmaxf(acc[5][reg] + bv[5], 0.f);
            fb.z = fmaxf(acc[6][reg] + bv[6], 0.f);
            fb.w = fmaxf(acc[7][reg] + bv[7], 0.f);
            float* row = out + (size_t)node * FEAT + n16 * 8;
            *(float4*)row       = fa;
            *(float4*)(row + 4) = fb;
        }
    }
}

// ============================ launch ============================

extern "C" void kernel_launch(void* const* d_in, const int* in_sizes, int n_in,
                              void* d_out, int out_size, void* d_ws, size_t ws_size,
                              hipStream_t stream) {
    const float* h    = (const float*)d_in[0];
    const float* wgt  = (const float*)d_in[1];
    const float* wcmp = (const float*)d_in[2];
    const float* rw   = (const float*)d_in[3];
    const float* bias = (const float*)d_in[4];
    const int*   src  = (const int*)d_in[5];
    const int*   dst  = (const int*)d_in[6];
    const int*   rel  = (const int*)d_in[7];
    float* out = (float*)d_out;

    char* ws = (char*)d_ws;
    short*        hb     = (short*)(ws + 0);
    short*        Btf    = (short*)(ws + 25600000ull);
    short*        z      = (short*)(ws + 25763840ull);
    unsigned int* z_u32  = (unsigned int*)z;
    int*          packed = (int*)(ws + 128163840ull);
    int*          cnt    = (int*)(ws + 130563840ull);
    int*          offs   = (int*)(ws + 130963840ull);
    int*          cursor = (int*)(ws + 131363968ull);
    int*          status = (int*)(ws + 131763968ull);

    hipLaunchKernelGGL(k_prep,     dim3(PREP_GRID), dim3(256), 0, stream,
                       h, wgt, rw, hb, Btf, cnt, status);
    hipLaunchKernelGGL(k_hist_dst, dim3(NBE),  dim3(256), 0, stream, dst, cnt);
    hipLaunchKernelGGL(k_scan_lb,  dim3(SCAN_TILES), dim3(256), 0, stream,
                       cnt, offs, cursor, status);
    hipLaunchKernelGGL(k_scatter_sorted, dim3(NBE), dim3(256), 0, stream,
                       src, dst, rel, cursor, packed);
    hipLaunchKernelGGL(k_edge_z,   dim3(N_NODES / 8), dim3(256), 0, stream,
                       offs, packed, wcmp, hb, z_u32);
    hipLaunchKernelGGL(k_gemm_fused, dim3((N_NODES + 63) / 64), dim3(256), 0, stream,
                       hb, z, Btf, bias, out);
}

// Round 10
// 252.395 us; speedup vs baseline: 1.0162x; 1.0162x over previous
//
#include <hip/hip_runtime.h>
#include <hip/hip_bf16.h>

#define N_NODES 100000
#define N_EDGES 600000
#define FEAT 128
#define NUM_RELS 8
#define NUM_BASES 4
#define NBE 2344    // ceil(N_EDGES/256)

// grid partition for k_prep
#define PREP_CAST 6250                   // cast_h blocks (6250*256*8 = 12.8M bf16)
#define PREP_BLDB 320                    // build_b blocks (320*256 = 81920 = 5*128*128)
#define PREP_ZERO 392                    // cnt (100000) + scan status (128) zero blocks
#define PREP_GRID (PREP_CAST + PREP_BLDB + PREP_ZERO)

#define SCAN_TILES 98                    // ceil(25000 int4 / 256)

typedef short bf16x8 __attribute__((ext_vector_type(8)));
typedef float f32x4  __attribute__((ext_vector_type(4)));
typedef float f32x2  __attribute__((ext_vector_type(2)));

__device__ inline short f2bf(float x) {
    __hip_bfloat16 b = __float2bfloat16(x);
    return *reinterpret_cast<short*>(&b);
}

// ws layout (bytes):
//   hb     bf16[N*128]       @ 0            25,600,000
//   Btf    bf16[5*128*128]   @ 25,600,000   163,840   (FRAGMENT-MAJOR, see k_prep)
//   z      bf16[N*512]       @ 25,763,840   102,400,000  ([d][b*128+i])
//   packed int[E]            @ 128,163,840  2,400,000 (dst-sorted (src<<3)|rel)
//   cnt    int[N]            @ 130,563,840  400,000
//   offs   int[N+1 pad]      @ 130,963,840  400,128
//   cursor int[N]            @ 131,363,968  400,000
//   status int[128]          @ 131,763,968  512      (lookback-scan tile status)
// total ~131.8 MB

// ---------- k_prep: cast h->bf16 | build fragment-major B | zero cnt+status ----------
// Btf stored in EXACT per-lane MFMA fragment order (verified rounds 3-9):
//   lane l (quad=l>>4, n16=l&15) of frag (kc,ks,nt) holds
//   Bt[kc][o=n16*8+nt][ip=ks*32+quad*8 .. +8)   (Bt[o][i] = B[i][o])
// Position (in shorts): ((kc*4+ks)*8 + nt)*512 + lane*8 + j.
__global__ __launch_bounds__(256) void k_prep(const float* __restrict__ h,
                                              const float* __restrict__ weight,
                                              const float* __restrict__ rw,
                                              short* __restrict__ hb,
                                              short* __restrict__ Btf,
                                              int* __restrict__ cnt,
                                              int* __restrict__ status) {
    int b = blockIdx.x;
    if (b < PREP_CAST) {
        int i = b * 256 + threadIdx.x;                 // < 1.6M exactly
        const float4* h4 = (const float4*)h;
        float4 v0 = h4[2 * i], v1 = h4[2 * i + 1];
        union { short s[8]; bf16x8 v; } u;
        u.s[0] = f2bf(v0.x); u.s[1] = f2bf(v0.y); u.s[2] = f2bf(v0.z); u.s[3] = f2bf(v0.w);
        u.s[4] = f2bf(v1.x); u.s[5] = f2bf(v1.y); u.s[6] = f2bf(v1.z); u.s[7] = f2bf(v1.w);
        ((bf16x8*)hb)[i] = u.v;
    } else if (b < PREP_CAST + PREP_BLDB) {
        int idx = (b - PREP_CAST) * 256 + threadIdx.x; // < 81920 exactly
        int kc = idx >> 14;
        int e  = idx & 16383;
        int o  = e >> 7, ip = e & 127;
        float v = (kc == 0) ? rw[ip * FEAT + o]
                            : weight[(kc - 1) * FEAT * FEAT + ip * FEAT + o];
        int nt = o & 7, n16 = o >> 3;
        int ks = ip >> 5, quad = (ip >> 3) & 3, j = ip & 7;
        int lane = quad * 16 + n16;
        Btf[((kc * 4 + ks) * 8 + nt) * 512 + lane * 8 + j] = f2bf(v);
    } else {
        int i = (b - PREP_CAST - PREP_BLDB) * 256 + threadIdx.x;
        if (i < N_NODES) cnt[i] = 0;
        else if (i - N_NODES < 128) status[i - N_NODES] = 0;
    }
}

// ---------- dst histogram ----------
__global__ __launch_bounds__(256) void k_hist_dst(const int* __restrict__ dst,
                                                  int* __restrict__ cnt) {
    int i = blockIdx.x * 256 + threadIdx.x;
    if (i < N_EDGES) atomicAdd(&cnt[dst[i]], 1);       // 100K bins, ~6/bin
}

// ---------- decoupled-lookback exclusive scan: WAVE-PARALLEL lookback ----------
__global__ __launch_bounds__(256) void k_scan_lb(const int* __restrict__ cnt,
                                                 int* __restrict__ offs,
                                                 int* __restrict__ cursor,
                                                 int* __restrict__ status) {
    __shared__ int wsum[4];
    __shared__ int bcast;
    int bid = blockIdx.x;
    int lane = threadIdx.x & 63, wid = threadIdx.x >> 6;
    const int N4 = N_NODES / 4;                        // 25000
    int i4 = bid * 256 + threadIdx.x;

    const int4* cnt4 = (const int4*)cnt;
    int4 v = (i4 < N4) ? cnt4[i4] : make_int4(0, 0, 0, 0);
    int s = v.x + v.y + v.z + v.w;
    int incl = s;
#pragma unroll
    for (int d = 1; d < 64; d <<= 1) {
        int t = __shfl_up(incl, d);
        if (lane >= d) incl += t;
    }
    if (lane == 63) wsum[wid] = incl;
    __syncthreads();
    int total = wsum[0] + wsum[1] + wsum[2] + wsum[3];

    if (threadIdx.x < 64) {                            // wave 0 does the lookback
        int excl = 0;
        if (bid > 0) {
            if (lane == 0)
                __hip_atomic_store(&status[bid], (total << 2) | 1,
                                   __ATOMIC_RELEASE, __HIP_MEMORY_SCOPE_AGENT);
            int winEnd = bid;                          // window covers [winEnd-64, winEnd)
            for (;;) {
                int idx = winEnd - 64 + lane;
                int st = 2;                            // idx<0: prefix 0, done
                if (idx >= 0) {
                    st = __hip_atomic_load(&status[idx],
                                           __ATOMIC_ACQUIRE, __HIP_MEMORY_SCOPE_AGENT);
                    while ((st & 3) == 0) {
                        __builtin_amdgcn_s_sleep(1);
                        st = __hip_atomic_load(&status[idx],
                                               __ATOMIC_ACQUIRE, __HIP_MEMORY_SCOPE_AGENT);
                    }
                }
                unsigned long long done = __ballot((st & 3) == 2);
                int contrib;
                if (done) {
                    int L = 63 - __builtin_clzll(done);    // nearest prefix-done
                    contrib = (lane >= L) ? (st >> 2) : 0; // lane L: prefix; above: aggregates
                } else {
                    contrib = st >> 2;                     // all aggregates, keep walking
                }
#pragma unroll
                for (int m = 1; m < 64; m <<= 1) contrib += __shfl_xor(contrib, m);
                excl += contrib;
                if (done) break;
                winEnd -= 64;
            }
        }
        if (lane == 0) {
            __hip_atomic_store(&status[bid], ((excl + total) << 2) | 2,
                               __ATOMIC_RELEASE, __HIP_MEMORY_SCOPE_AGENT);
            bcast = excl;
            if (bid == SCAN_TILES - 1) offs[N_NODES] = excl + total;   // == N_EDGES
        }
    }
    __syncthreads();
    int wexcl = 0;
#pragma unroll
    for (int w = 0; w < 4; ++w) if (w < wid) wexcl += wsum[w];
    int base = bcast + wexcl + incl - s;
    if (i4 < N4) {
        int4 ex;
        ex.x = base;
        ex.y = base + v.x;
        ex.z = base + v.x + v.y;
        ex.w = base + v.x + v.y + v.z;
        ((int4*)offs)[i4]   = ex;
        ((int4*)cursor)[i4] = ex;
    }
}

// ---------- scatter: dst-sorted packed (src<<3)|rel — one 4B word per edge ----------
__global__ __launch_bounds__(256) void k_scatter_sorted(const int* __restrict__ src,
                                                        const int* __restrict__ dst,
                                                        const int* __restrict__ rel,
                                                        int* __restrict__ cursor,
                                                        int* __restrict__ packed) {
    int e = blockIdx.x * 256 + threadIdx.x;
    if (e < N_EDGES) {
        int p = atomicAdd(&cursor[dst[e]], 1);         // ~6-way contention
        packed[p] = (src[e] << 3) | rel[e];
    }
}

// ---------- edge phase: z[d][b][:] = sum_{e->d} w_comp[rel,b] * h[src] ----------
// TWO dst streams per wave (verified round 6). Per-dst FP accumulation order is
// ascending edge index — bit-identical to the single-stream version.
#define RL(pk, j) __builtin_amdgcn_readlane(pk, j)
#define EDGE_ACC(zz, c, v)                                               \
    {   f32x2 hh; hh.x = __int_as_float((v) << 16);                      \
        hh.y = __int_as_float((v) & 0xffff0000u);                        \
        f32x2 cc;                                                        \
        cc = c.x; zz[0] += cc * hh;                                      \
        cc = c.y; zz[1] += cc * hh;                                      \
        cc = c.z; zz[2] += cc * hh;                                      \
        cc = c.w; zz[3] += cc * hh; }

__global__ __launch_bounds__(256) void k_edge_z(const int* __restrict__ offs,
                                                const int* __restrict__ packed,
                                                const float* __restrict__ wc,
                                                const short* __restrict__ hb,
                                                unsigned int* __restrict__ z_u32) {
    int wid = threadIdx.x >> 6, lane = threadIdx.x & 63;
    int d0 = blockIdx.x * 8 + wid * 2;                 // grid 12500 -> exact, no tail
    int s0 = offs[d0], sM = offs[d0 + 1], e1 = offs[d0 + 2];

    const float4* wc4 = (const float4*)wc;             // uniform idx -> s_load_dwordx4
    const unsigned int* hbu = (const unsigned int*)hb; // 64 u32 per node row

    f32x2 za[4] = {(f32x2)0.f, (f32x2)0.f, (f32x2)0.f, (f32x2)0.f};
    f32x2 zb[4] = {(f32x2)0.f, (f32x2)0.f, (f32x2)0.f, (f32x2)0.f};

    int baseA = s0, baseB = sM;
    while (baseA < sM || baseB < e1) {
        int mA = sM - baseA; mA = mA < 0 ? 0 : (mA > 64 ? 64 : mA);
        int mB = e1 - baseB; mB = mB < 0 ? 0 : (mB > 64 ? 64 : mB);
        int pkA = (lane < mA) ? packed[baseA + lane] : 0;
        int pkB = (lane < mB) ? packed[baseB + lane] : 0;
        int jA = 0, jB = 0;

        // joint 4+4: 8 independent gathers in flight
        while (jA + 3 < mA && jB + 3 < mB) {
            int a0 = RL(pkA, jA), a1 = RL(pkA, jA + 1), a2 = RL(pkA, jA + 2), a3 = RL(pkA, jA + 3);
            int b0 = RL(pkB, jB), b1 = RL(pkB, jB + 1), b2 = RL(pkB, jB + 2), b3 = RL(pkB, jB + 3);
            unsigned int va0 = hbu[(size_t)(a0 >> 3) * 64 + lane];
            unsigned int va1 = hbu[(size_t)(a1 >> 3) * 64 + lane];
            unsigned int va2 = hbu[(size_t)(a2 >> 3) * 64 + lane];
            unsigned int va3 = hbu[(size_t)(a3 >> 3) * 64 + lane];
            unsigned int vb0 = hbu[(size_t)(b0 >> 3) * 64 + lane];
            unsigned int vb1 = hbu[(size_t)(b1 >> 3) * 64 + lane];
            unsigned int vb2 = hbu[(size_t)(b2 >> 3) * 64 + lane];
            unsigned int vb3 = hbu[(size_t)(b3 >> 3) * 64 + lane];
            float4 ca0 = wc4[a0 & 7], ca1 = wc4[a1 & 7], ca2 = wc4[a2 & 7], ca3 = wc4[a3 & 7];
            float4 cb0 = wc4[b0 & 7], cb1 = wc4[b1 & 7], cb2 = wc4[b2 & 7], cb3 = wc4[b3 & 7];
            EDGE_ACC(za, ca0, va0); EDGE_ACC(za, ca1, va1);
            EDGE_ACC(za, ca2, va2); EDGE_ACC(za, ca3, va3);
            EDGE_ACC(zb, cb0, vb0); EDGE_ACC(zb, cb1, vb1);
            EDGE_ACC(zb, cb2, vb2); EDGE_ACC(zb, cb3, vb3);
            jA += 4; jB += 4;
        }
        // joint 1+1: overlap the two tails (2 in flight)
        while (jA < mA && jB < mB) {
            int a0 = RL(pkA, jA), b0 = RL(pkB, jB);
            unsigned int va0 = hbu[(size_t)(a0 >> 3) * 64 + lane];
            unsigned int vb0 = hbu[(size_t)(b0 >> 3) * 64 + lane];
            float4 ca0 = wc4[a0 & 7], cb0 = wc4[b0 & 7];
            EDGE_ACC(za, ca0, va0);
            EDGE_ACC(zb, cb0, vb0);
            ++jA; ++jB;
        }
        // drain A
        while (jA + 3 < mA) {
            int a0 = RL(pkA, jA), a1 = RL(pkA, jA + 1), a2 = RL(pkA, jA + 2), a3 = RL(pkA, jA + 3);
            unsigned int va0 = hbu[(size_t)(a0 >> 3) * 64 + lane];
            unsigned int va1 = hbu[(size_t)(a1 >> 3) * 64 + lane];
            unsigned int va2 = hbu[(size_t)(a2 >> 3) * 64 + lane];
            unsigned int va3 = hbu[(size_t)(a3 >> 3) * 64 + lane];
            float4 ca0 = wc4[a0 & 7], ca1 = wc4[a1 & 7], ca2 = wc4[a2 & 7], ca3 = wc4[a3 & 7];
            EDGE_ACC(za, ca0, va0); EDGE_ACC(za, ca1, va1);
            EDGE_ACC(za, ca2, va2); EDGE_ACC(za, ca3, va3);
            jA += 4;
        }
        while (jA < mA) {
            int a0 = RL(pkA, jA);
            unsigned int va0 = hbu[(size_t)(a0 >> 3) * 64 + lane];
            float4 ca0 = wc4[a0 & 7];
            EDGE_ACC(za, ca0, va0);
            ++jA;
        }
        // drain B
        while (jB + 3 < mB) {
            int b0 = RL(pkB, jB), b1 = RL(pkB, jB + 1), b2 = RL(pkB, jB + 2), b3 = RL(pkB, jB + 3);
            unsigned int vb0 = hbu[(size_t)(b0 >> 3) * 64 + lane];
            unsigned int vb1 = hbu[(size_t)(b1 >> 3) * 64 + lane];
            unsigned int vb2 = hbu[(size_t)(b2 >> 3) * 64 + lane];
            unsigned int vb3 = hbu[(size_t)(b3 >> 3) * 64 + lane];
            float4 cb0 = wc4[b0 & 7], cb1 = wc4[b1 & 7], cb2 = wc4[b2 & 7], cb3 = wc4[b3 & 7];
            EDGE_ACC(zb, cb0, vb0); EDGE_ACC(zb, cb1, vb1);
            EDGE_ACC(zb, cb2, vb2); EDGE_ACC(zb, cb3, vb3);
            jB += 4;
        }
        while (jB < mB) {
            int b0 = RL(pkB, jB);
            unsigned int vb0 = hbu[(size_t)(b0 >> 3) * 64 + lane];
            float4 cb0 = wc4[b0 & 7];
            EDGE_ACC(zb, cb0, vb0);
            ++jB;
        }
        baseA += 64; baseB += 64;
    }

    unsigned int* row0 = z_u32 + (size_t)d0 * 256;     // 512 bf16 = 256 u32
    unsigned int* row1 = row0 + 256;
#pragma unroll
    for (int b = 0; b < 4; ++b) {
        unsigned int lo0 = ((unsigned int)(unsigned short)f2bf(za[b].x));
        unsigned int hi0 = ((unsigned int)(unsigned short)f2bf(za[b].y)) << 16;
        row0[b * 64 + lane] = lo0 | hi0;
        unsigned int lo1 = ((unsigned int)(unsigned short)f2bf(zb[b].x));
        unsigned int hi1 = ((unsigned int)(unsigned short)f2bf(zb[b].y)) << 16;
        row1[b * 64 + lane] = lo1 | hi1;
    }
}

// ---------- fused GEMM: out = relu([hb | z] @ B + bias), K=640 ----------
// M=32/wave + conflict-free frag-major LDS (the untested design-matrix cell):
// each B fragment ds_read feeds TWO MFMAs (rows base+n16, base+16+n16) —
// halves LDS-read traffic per MFMA vs M=16 (1 GB -> 0.5 GB block-aggregate)
// and halves per-output-row barrier count. 128-row block, 4 waves, grid 782.
// Next-kc A prefetched after the DMA barrier (round-6 form).
__global__ __launch_bounds__(256) void k_gemm_fused(const short* __restrict__ hb,
                                                    const short* __restrict__ z,
                                                    const short* __restrict__ Btf,
                                                    const float* __restrict__ bias,
                                                    float* __restrict__ out) {
    __shared__ short lds[FEAT * FEAT];                  // 32 KB (one K-chunk, frag-major)
    int wave = threadIdx.x >> 6, lane = threadIdx.x & 63;
    int quad = lane >> 4, n16 = lane & 15;
    int base = blockIdx.x * 128 + wave * 32;

    int rowA0 = base + n16;        if (rowA0 >= N_NODES) rowA0 = N_NODES - 1;
    int rowA1 = base + 16 + n16;   if (rowA1 >= N_NODES) rowA1 = N_NODES - 1;

    f32x4 acc[2][8];
#pragma unroll
    for (int mt = 0; mt < 2; ++mt)
#pragma unroll
        for (int nt = 0; nt < 8; ++nt) acc[mt][nt] = (f32x4)0.f;

    const bf16x8* bp = (const bf16x8*)lds;
    char* lds_base = (char*)lds;

    // preload kc=0 A-fragments (from hb)
    bf16x8 a_cur[2][4];
    {
        const bf16x8* a0p = (const bf16x8*)(hb + (size_t)rowA0 * FEAT);
        const bf16x8* a1p = (const bf16x8*)(hb + (size_t)rowA1 * FEAT);
#pragma unroll
        for (int ks = 0; ks < 4; ++ks) {
            a_cur[0][ks] = a0p[ks * 4 + quad];
            a_cur[1][ks] = a1p[ks * 4 + quad];
        }
    }

    for (int kc = 0; kc < 5; ++kc) {
        if (kc) __syncthreads();                        // drain reads before restage
        const char* gsrc = (const char*)Btf + kc * 32768;
#pragma unroll
        for (int t = 0; t < 8; ++t) {
            unsigned int off = wave * 8192 + t * 1024;
            __builtin_amdgcn_global_load_lds(
                (const __attribute__((address_space(1))) unsigned int*)(gsrc + off + lane * 16),
                (__attribute__((address_space(3))) unsigned int*)(lds_base + off),
                16, 0, 0);
        }
        __syncthreads();                                // DMA complete

        // prefetch next kc's A (z rows) — latency hides under this kc's MFMAs
        bf16x8 a_nxt[2][4];
        if (kc < 4) {
            const bf16x8* a0p = (const bf16x8*)(z + (size_t)rowA0 * 512 + kc * FEAT);
            const bf16x8* a1p = (const bf16x8*)(z + (size_t)rowA1 * 512 + kc * FEAT);
#pragma unroll
            for (int ks = 0; ks < 4; ++ks) {
                a_nxt[0][ks] = a0p[ks * 4 + quad];
                a_nxt[1][ks] = a1p[ks * 4 + quad];
            }
        }

#pragma unroll
        for (int ks = 0; ks < 4; ++ks) {
            const bf16x8* bks = bp + ks * 512 + lane;   // contiguous 1KB per frag
#pragma unroll
            for (int nt = 0; nt < 8; ++nt) {
                bf16x8 b = bks[nt * 64];                // one read, two MFMAs
                acc[0][nt] = __builtin_amdgcn_mfma_f32_16x16x32_bf16(a_cur[0][ks], b, acc[0][nt], 0, 0, 0);
                acc[1][nt] = __builtin_amdgcn_mfma_f32_16x16x32_bf16(a_cur[1][ks], b, acc[1][nt], 0, 0, 0);
            }
        }

        if (kc < 4) {
#pragma unroll
            for (int ks = 0; ks < 4; ++ks) {
                a_cur[0][ks] = a_nxt[0][ks];
                a_cur[1][ks] = a_nxt[1][ks];
            }
        }
    }

    float bv[8];
#pragma unroll
    for (int nt = 0; nt < 8; ++nt) bv[nt] = bias[n16 * 8 + nt];

#pragma unroll
    for (int mt = 0; mt < 2; ++mt)
#pragma unroll
        for (int reg = 0; reg < 4; ++reg) {
            int node = base + mt * 16 + quad * 4 + reg;
            if (node < N_NODES) {
                float4 fa, fb;
                fa.x = fmaxf(acc[mt][0][reg] + bv[0], 0.f);
                fa.y = fmaxf(acc[mt][1][reg] + bv[1], 0.f);
                fa.z = fmaxf(acc[mt][2][reg] + bv[2], 0.f);
                fa.w = fmaxf(acc[mt][3][reg] + bv[3], 0.f);
                fb.x = fmaxf(acc[mt][4][reg] + bv[4], 0.f);
                fb.y = fmaxf(acc[mt][5][reg] + bv[5], 0.f);
                fb.z = fmaxf(acc[mt][6][reg] + bv[6], 0.f);
                fb.w = fmaxf(acc[mt][7][reg] + bv[7], 0.f);
                float* row = out + (size_t)node * FEAT + n16 * 8;
                *(float4*)row       = fa;
                *(float4*)(row + 4) = fb;
            }
        }
}

// ============================ launch ============================

extern "C" void kernel_launch(void* const* d_in, const int* in_sizes, int n_in,
                              void* d_out, int out_size, void* d_ws, size_t ws_size,
                              hipStream_t stream) {
    const float* h    = (const float*)d_in[0];
    const float* wgt  = (const float*)d_in[1];
    const float* wcmp = (const float*)d_in[2];
    const float* rw   = (const float*)d_in[3];
    const float* bias = (const float*)d_in[4];
    const int*   src  = (const int*)d_in[5];
    const int*   dst  = (const int*)d_in[6];
    const int*   rel  = (const int*)d_in[7];
    float* out = (float*)d_out;

    char* ws = (char*)d_ws;
    short*        hb     = (short*)(ws + 0);
    short*        Btf    = (short*)(ws + 25600000ull);
    short*        z      = (short*)(ws + 25763840ull);
    unsigned int* z_u32  = (unsigned int*)z;
    int*          packed = (int*)(ws + 128163840ull);
    int*          cnt    = (int*)(ws + 130563840ull);
    int*          offs   = (int*)(ws + 130963840ull);
    int*          cursor = (int*)(ws + 131363968ull);
    int*          status = (int*)(ws + 131763968ull);

    hipLaunchKernelGGL(k_prep,     dim3(PREP_GRID), dim3(256), 0, stream,
                       h, wgt, rw, hb, Btf, cnt, status);
    hipLaunchKernelGGL(k_hist_dst, dim3(NBE),  dim3(256), 0, stream, dst, cnt);
    hipLaunchKernelGGL(k_scan_lb,  dim3(SCAN_TILES), dim3(256), 0, stream,
                       cnt, offs, cursor, status);
    hipLaunchKernelGGL(k_scatter_sorted, dim3(NBE), dim3(256), 0, stream,
                       src, dst, rel, cursor, packed);
    hipLaunchKernelGGL(k_edge_z,   dim3(N_NODES / 8), dim3(256), 0, stream,
                       offs, packed, wcmp, hb, z_u32);
    hipLaunchKernelGGL(k_gemm_fused, dim3((N_NODES + 127) / 128), dim3(256), 0, stream,
                       hb, z, Btf, bias, out);
}